// Round 14
// baseline (131.920 us; speedup 1.0000x reference)
//
#include <hip/hip_runtime.h>
#include <hip/hip_bf16.h>

typedef __bf16 bf16x8 __attribute__((ext_vector_type(8)));
typedef float  f32x4  __attribute__((ext_vector_type(4)));

#define B_SZ 4096
#define I_SZ 512
#define O_SZ 64
#define E_SZ 128
#define BM   256
#define G_EXP 8      // experts per workgroup (K-split group size)
#define EG_N  16     // expert groups
#define MT_N  16     // m tiles (4096/256)

// ---------------- fused prep: x f32->bf16  +  gT[e][b] ----------------
__global__ void prep_xg(const float* __restrict__ x, __bf16* __restrict__ xb,
                        const float* __restrict__ ds, const float* __restrict__ ts,
                        float* __restrict__ gT) {
  int i = blockIdx.x * 256 + threadIdx.x;          // 524288 = B*I/4 = E*B
  float4 v = ((const float4*)x)[i];
  union { __bf16 h[4]; ushort4 u4; } pk;
  pk.h[0] = (__bf16)v.x; pk.h[1] = (__bf16)v.y;
  pk.h[2] = (__bf16)v.z; pk.h[3] = (__bf16)v.w;
  ((ushort4*)xb)[i] = pk.u4;
  int e = i >> 12, b = i & 4095;
  gT[i] = ds[b * 32 + (e >> 2)] * ts[b * 4 + (e & 3)];
}

// ---------------- prep: W [e][i][o] f32 -> wt [e][o][i] bf16 ----------------
__global__ void prep_w(const float* __restrict__ W, __bf16* __restrict__ wt) {
  __shared__ __bf16 tile[64][66];
  int e  = blockIdx.x >> 3;
  int it = blockIdx.x & 7;
  const float* src = W + (size_t)e * I_SZ * O_SZ + (size_t)it * 64 * O_SZ;
  #pragma unroll
  for (int s = 0; s < 16; ++s) {
    int idx = s * 256 + threadIdx.x;
    int r = idx >> 6, o = idx & 63;
    tile[o][r] = (__bf16)src[idx];
  }
  __syncthreads();
  __bf16* dst = wt + (size_t)e * O_SZ * I_SZ + it * 64;
  #pragma unroll
  for (int s = 0; s < 4; ++s) {
    int idx = s * 256 + threadIdx.x;
    int o = idx >> 4, c = (idx & 15) << 2;
    union { __bf16 h[4]; ushort4 u4; } q;
    q.h[0] = tile[o][c + 0]; q.h[1] = tile[o][c + 1];
    q.h[2] = tile[o][c + 2]; q.h[3] = tile[o][c + 3];
    *(ushort4*)&dst[(size_t)o * I_SZ + c] = q.u4;
  }
}

// ---------------- main: 64-row waves via K-split, R9 schedule, no exchange -----
// 8 waves = 4 row-groups(64 r) x 2 K-halves(256 k each). Wave covers (64r,64o,256k):
// af stays 128 VGPR (2 waves/SIMD), LDS B-reads HALVE vs R9 (32 b128/wave/expert,
// 256KB/CU-phase). No K-half exchange (R12's spill source): each wave writes its
// gated bf16 partial to its own parts slab; reduce sums 32 slabs. nf-outer keeps
// live acc=16 regs (budget ~233 < 256). Schedule/stage/LDS byte-identical to R9:
// chunked zero-conflict layout, 2 barriers + counted vmcnt(8) per expert.
// Bias folded at kh=0 only. Spill detector: FETCH_SIZE > 26MB.
__global__ __launch_bounds__(512, 2)
void mtc_gemm(const __bf16* __restrict__ xb, const __bf16* __restrict__ wt,
              const float* __restrict__ gT, const float* __restrict__ bias,
              __bf16* __restrict__ partials) {
  __shared__ __align__(16) __bf16 wsh[2][8][64 * 64];  // [buf][kc][o*64+slot*8] 8KB chunks
  __shared__ float gsh[G_EXP][BM];                     // 8KB gates
  __shared__ float bsh[G_EXP][O_SZ];                   // 2KB bias

  const int tid  = threadIdx.x;
  const int wave = tid >> 6;
  const int lane = tid & 63;
  const int rg   = wave >> 1;                          // row-group: 64 rows
  const int kh   = wave & 1;                           // K-half: chunks kh*4 .. kh*4+3

  // XCD swizzle: 256 blocks -> 32 consecutive per XCD
  int bid = (int)blockIdx.x;
  bid = (bid & 7) * 32 + (bid >> 3);
  const int mtile = bid & 15;
  const int eg    = bid >> 4;
  const int row0  = mtile * BM;
  const int e0    = eg * G_EXP;

  // stage whole expert e into wsh[sbuf]: 8 DMAs/thread (512 thr x 16B x 8 = 64KB).
  // dest linear => [o=tid>>3][slot p=tid&7]; source slot sl = p^(o&7) (involution).
  auto stage = [&](int sbuf, int e) {
    const __bf16* wsrc = wt + (size_t)(e0 + e) * O_SZ * I_SZ;
    int o = tid >> 3, p = tid & 7;
    int sl = p ^ (o & 7);
    #pragma unroll
    for (int kc = 0; kc < 8; ++kc) {
      __builtin_amdgcn_global_load_lds(
          (const __attribute__((address_space(1))) void*)(wsrc + (size_t)o * I_SZ + kc * 64 + sl * 8),
          (__attribute__((address_space(3))) void*)(&wsh[sbuf][kc][wave * 512]),
          16, 0, 0);
    }
  };

  // prologue: stage expert 0, overlap with gsh + bias + af loads
  stage(0, 0);

  for (int idx = tid; idx < G_EXP * BM; idx += 512)
    gsh[idx >> 8][idx & 255] =
        gT[(size_t)(e0 + (idx >> 8)) * B_SZ + row0 + (idx & 255)];

  bsh[tid >> 6][tid & 63] = bias[(size_t)e0 * O_SZ + tid];   // 512 = G_EXP*O_SZ

  // af[mf][j] = x[row0 + rg*64 + mf*16 + (lane&15)][kh*256 + j*32 + (lane>>4)*8 ..+8]
  bf16x8 af[4][8];                                   // 128 VGPR
  {
    const __bf16* xr = xb + (size_t)(row0 + rg * 64 + (lane & 15)) * I_SZ
                          + kh * 256 + (lane >> 4) * 8;
    #pragma unroll
    for (int mf = 0; mf < 4; ++mf)
      #pragma unroll
      for (int j = 0; j < 8; ++j)
        af[mf][j] = *(const bf16x8*)(xr + mf * 16 * I_SZ + j * 32);
  }

  __syncthreads();                     // drains DMA(e0) + af + bias + gsh (vmcnt->0)

  f32x4 logits[4][4] = {};             // 64 VGPR: this wave's gated K-half partial
  int buf = 0;
  for (int e = 0; e < G_EXP; ++e) {
    if (e < G_EXP - 1) {
      stage(buf ^ 1, e + 1);                       // 8 DMAs into other buffer
      asm volatile("s_waitcnt vmcnt(8)" ::: "memory");   // stage(e) landed
    } else {
      asm volatile("s_waitcnt vmcnt(0)" ::: "memory");
    }
    __builtin_amdgcn_s_barrier();                  // buf ready for all waves

    #pragma unroll
    for (int nf = 0; nf < 4; ++nf) {               // nf-outer: acc only 16 regs live
      const int o = nf * 16 + (lane & 15);
      float bv = kh ? 0.f : bsh[e][o];             // bias once (kh=0 waves)
      f32x4 acc[4];
      #pragma unroll
      for (int mf = 0; mf < 4; ++mf)
        acc[mf] = (f32x4){bv, bv, bv, bv};

      __builtin_amdgcn_s_setprio(1);
      #pragma unroll
      for (int j = 0; j < 8; ++j) {                // this wave's K-half: 8 K32-steps
        const __bf16* wb = &wsh[buf][kh * 4 + (j >> 1)][0];
        int q  = (j & 1) * 4 + (lane >> 4);
        int ph = q ^ (o & 7);
        bf16x8 bfr = *(const bf16x8*)(wb + o * 64 + ph * 8);
        #pragma unroll
        for (int mf = 0; mf < 4; ++mf)
          acc[mf] = __builtin_amdgcn_mfma_f32_16x16x32_bf16(
              af[mf][j], bfr, acc[mf], 0, 0, 0);
      }
      __builtin_amdgcn_s_setprio(0);

      // immediate drain: logits += g * acc  (C/D: col=lane&15, row=(lane>>4)*4+rgi)
      #pragma unroll
      for (int mf = 0; mf < 4; ++mf) {
        f32x4 gq = *(const f32x4*)&gsh[e][rg * 64 + mf * 16 + (lane >> 4) * 4];
        #pragma unroll
        for (int rgi = 0; rgi < 4; ++rgi)
          logits[mf][nf][rgi] += gq[rgi] * acc[mf][rgi];
      }
    }

    __builtin_amdgcn_s_barrier();                  // all waves done reading buf
    buf ^= 1;
  }

  // epilogue: write this wave's bf16 partial to its own slab (eg*2+kh)
  __bf16* pout = partials + (size_t)(eg * 2 + kh) * B_SZ * O_SZ
                          + (size_t)row0 * O_SZ;
  #pragma unroll
  for (int mf = 0; mf < 4; ++mf)
    #pragma unroll
    for (int nf = 0; nf < 4; ++nf)
      #pragma unroll
      for (int rgi = 0; rgi < 4; ++rgi) {
        int r = rg * 64 + mf * 16 + ((lane >> 4) << 2) + rgi;
        int o = nf * 16 + (lane & 15);
        pout[(size_t)r * O_SZ + o] = (__bf16)logits[mf][nf][rgi];
      }
}

// ---------------- reduce: sum 32 bf16 partial slabs + log_softmax --------------
__global__ __launch_bounds__(256)
void mtc_reduce(const __bf16* __restrict__ partials, float* __restrict__ out) {
  int wave = threadIdx.x >> 6, lane = threadIdx.x & 63;
  int r = blockIdx.x * 4 + wave;                    // one 64-lane wave per row
  float s = 0.f;
  #pragma unroll
  for (int k = 0; k < 2 * EG_N; ++k)
    s += (float)partials[(size_t)k * B_SZ * O_SZ + (size_t)r * O_SZ + lane];
  float m = s;
  #pragma unroll
  for (int off = 32; off; off >>= 1) m = fmaxf(m, __shfl_xor(m, off));
  float ex = expf(s - m), sum = ex;
  #pragma unroll
  for (int off = 32; off; off >>= 1) sum += __shfl_xor(sum, off);
  out[(size_t)r * O_SZ + lane] = s - m - logf(sum);
}

extern "C" void kernel_launch(void* const* d_in, const int* in_sizes, int n_in,
                              void* d_out, int out_size, void* d_ws, size_t ws_size,
                              hipStream_t stream) {
  const float* x    = (const float*)d_in[0];
  const float* ds   = (const float*)d_in[1];
  const float* ts   = (const float*)d_in[2];
  const float* W    = (const float*)d_in[3];
  const float* bias = (const float*)d_in[4];
  float* out = (float*)d_out;

  char* w = (char*)d_ws;
  __bf16* xb      = (__bf16*)(w);                   // 4 MB
  __bf16* wt      = (__bf16*)(w + (4ull  << 20));   // 8 MB
  float*  gT      = (float*) (w + (12ull << 20));   // 2 MB
  __bf16* parts   = (__bf16*)(w + (14ull << 20));   // 16 MB (32 slabs x 512KB)

  prep_xg   <<<2048, 256, 0, stream>>>(x, xb, ds, ts, gT);
  prep_w    <<<1024, 256, 0, stream>>>(W, wt);
  mtc_gemm  <<< 256, 512, 0, stream>>>(xb, wt, gT, bias, parts);
  mtc_reduce<<<1024, 256, 0, stream>>>(parts, out);
}

// Round 15
// 117.506 us; speedup vs baseline: 1.1227x; 1.1227x over previous
//
#include <hip/hip_runtime.h>
#include <hip/hip_bf16.h>

typedef __bf16 bf16x8 __attribute__((ext_vector_type(8)));
typedef float  f32x4  __attribute__((ext_vector_type(4)));

#define B_SZ 4096
#define I_SZ 512
#define O_SZ 64
#define E_SZ 128
#define BM   128     // 4 waves x 32 rows
#define G_EXP 8      // experts per workgroup (K-split group size)
#define EG_N  16     // expert groups
#define MT_N  32     // m tiles (4096/128)

// ---------------- fused prep: x f32->bf16  +  gT[e][b] ----------------
__global__ void prep_xg(const float* __restrict__ x, __bf16* __restrict__ xb,
                        const float* __restrict__ ds, const float* __restrict__ ts,
                        float* __restrict__ gT) {
  int i = blockIdx.x * 256 + threadIdx.x;          // 524288 = B*I/4 = E*B
  float4 v = ((const float4*)x)[i];
  union { __bf16 h[4]; ushort4 u4; } pk;
  pk.h[0] = (__bf16)v.x; pk.h[1] = (__bf16)v.y;
  pk.h[2] = (__bf16)v.z; pk.h[3] = (__bf16)v.w;
  ((ushort4*)xb)[i] = pk.u4;
  int e = i >> 12, b = i & 4095;
  gT[i] = ds[b * 32 + (e >> 2)] * ts[b * 4 + (e & 3)];
}

// ---------------- prep: W [e][i][o] f32 -> wt [e][o][i] bf16 ----------------
__global__ void prep_w(const float* __restrict__ W, __bf16* __restrict__ wt) {
  __shared__ __bf16 tile[64][66];
  int e  = blockIdx.x >> 3;
  int it = blockIdx.x & 7;
  const float* src = W + (size_t)e * I_SZ * O_SZ + (size_t)it * 64 * O_SZ;
  #pragma unroll
  for (int s = 0; s < 16; ++s) {
    int idx = s * 256 + threadIdx.x;
    int r = idx >> 6, o = idx & 63;
    tile[o][r] = (__bf16)src[idx];
  }
  __syncthreads();
  __bf16* dst = wt + (size_t)e * O_SZ * I_SZ + it * 64;
  #pragma unroll
  for (int s = 0; s < 4; ++s) {
    int idx = s * 256 + threadIdx.x;
    int o = idx >> 4, c = (idx & 15) << 2;
    union { __bf16 h[4]; ushort4 u4; } q;
    q.h[0] = tile[o][c + 0]; q.h[1] = tile[o][c + 1];
    q.h[2] = tile[o][c + 2]; q.h[3] = tile[o][c + 3];
    *(ushort4*)&dst[(size_t)o * I_SZ + c] = q.u4;
  }
}

// ---------------- main: 2 independent blocks/CU for LDS<->MFMA desync ---------
// 512 blocks x 256 thr (4 waves x 32 rows = BM 128), 70KB LDS -> 2 blocks/CU.
// Co-resident blocks share NO barrier: one block's MFMA cluster overlaps the
// other's LDS-read cluster (the overlap intra-block scheduling never produced:
// R6/R9/R13 all 14.4k cyc/phase = serial LDS 6.1k + MFMA 5.0k + overhead).
// Phase = half-expert (32KB, 16 phases). Per-wave reg profile BYTE-IDENTICAL to
// R9 (af[2][16]=128, acc 32, logits 32 -- the proven no-spill allocation).
// Chunked zero-conflict LDS (128B rows), counted vmcnt(8), 2 barriers/phase,
// bias folded at acc-init of each expert's first half-phase.
__global__ __launch_bounds__(256, 2)
void mtc_gemm(const __bf16* __restrict__ xb, const __bf16* __restrict__ wt,
              const float* __restrict__ gT, const float* __restrict__ bias,
              float* __restrict__ partials) {
  __shared__ __align__(16) __bf16 wsh[2][4][64 * 64];  // 2 buf x 4 chunks x 8KB = 64KB
  __shared__ float gsh[G_EXP][BM];                     // 4KB gates
  __shared__ float bsh[G_EXP][O_SZ];                   // 2KB bias

  const int tid  = threadIdx.x;
  const int wave = tid >> 6;                           // 0..3
  const int lane = tid & 63;

  // XCD swizzle: 512 blocks -> 64 consecutive per XCD
  int bid = (int)blockIdx.x;
  bid = (bid & 7) * 64 + (bid >> 3);
  const int mtile = bid & 31;
  const int eg    = bid >> 5;
  const int row0  = mtile * BM;
  const int e0    = eg * G_EXP;

  // stage half-expert (e, kh): 32KB = 4 chunks of [o][64k], 8 DMAs/thread.
  // dest linear: chunk[d>>1] byte (d&1)*4096 + tid*16  =>  o=(d&1)*32+(tid>>3),
  // phys slot p=tid&7; source slot sl = p^(o&7) (involution; read same XOR).
  auto stage = [&](int sbuf, int e, int kh) {
    const __bf16* wsrc = wt + (size_t)(e0 + e) * O_SZ * I_SZ + kh * 256;
    #pragma unroll
    for (int d = 0; d < 8; ++d) {
      int o  = (d & 1) * 32 + (tid >> 3);
      int sl = (tid & 7) ^ (o & 7);
      __builtin_amdgcn_global_load_lds(
          (const __attribute__((address_space(1))) void*)(wsrc + (size_t)o * I_SZ + (d >> 1) * 64 + sl * 8),
          (__attribute__((address_space(3))) void*)(&wsh[sbuf][d >> 1][(d & 1) * 2048 + tid * 8]),
          16, 0, 0);
    }
  };

  // prologue: stage (e0, kh0), overlap with gsh + bias + af loads
  stage(0, 0, 0);

  for (int idx = tid; idx < G_EXP * BM; idx += 256)
    gsh[idx >> 7][idx & 127] =
        gT[(size_t)(e0 + (idx >> 7)) * B_SZ + row0 + (idx & 127)];

  for (int idx = tid; idx < G_EXP * O_SZ; idx += 256)
    bsh[idx >> 6][idx & 63] = bias[(size_t)e0 * O_SZ + idx];

  // af[mf][jg] = x[row0+wave*32+mf*16+(lane&15)][jg*32+(lane>>4)*8 ..+8]  (full K)
  bf16x8 af[2][16];
  {
    const __bf16* xr = xb + (size_t)(row0 + wave * 32 + (lane & 15)) * I_SZ
                          + (lane >> 4) * 8;
    #pragma unroll
    for (int mf = 0; mf < 2; ++mf)
      #pragma unroll
      for (int jg = 0; jg < 16; ++jg)
        af[mf][jg] = *(const bf16x8*)(xr + mf * 16 * I_SZ + jg * 32);
  }

  __syncthreads();                     // drains DMA + af + bias + gsh (vmcnt->0)

  f32x4 logits[2][4] = {};
  f32x4 acc[2][4];
  int buf = 0;
  for (int ph = 0; ph < 2 * G_EXP; ++ph) {       // phase = (expert e, k-half kh)
    const int e  = ph >> 1;
    const int kh = ph & 1;
    if (ph < 2 * G_EXP - 1) {
      stage(buf ^ 1, (ph + 1) >> 1, (ph + 1) & 1);     // 8 DMAs, FIFO
      asm volatile("s_waitcnt vmcnt(8)" ::: "memory"); // this phase's 8 landed
    } else {
      asm volatile("s_waitcnt vmcnt(0)" ::: "memory");
    }
    __builtin_amdgcn_s_barrier();                // buf ready for all 4 waves

    if (!kh) {                                   // expert start: bias -> acc
      float bv[4];
      #pragma unroll
      for (int nf = 0; nf < 4; ++nf)
        bv[nf] = bsh[e][nf * 16 + (lane & 15)];
      #pragma unroll
      for (int mf = 0; mf < 2; ++mf)
        #pragma unroll
        for (int nf = 0; nf < 4; ++nf)
          acc[mf][nf] = (f32x4){bv[nf], bv[nf], bv[nf], bv[nf]};
    }

    __builtin_amdgcn_s_setprio(1);
    #pragma unroll
    for (int j = 0; j < 8; ++j) {                // k-quarter steps; chunk = j>>1
      const __bf16* wb = &wsh[buf][j >> 1][0];
      bf16x8 bfr[4];
      #pragma unroll
      for (int nf = 0; nf < 4; ++nf) {
        int o  = nf * 16 + (lane & 15);
        int q  = (j & 1) * 4 + (lane >> 4);
        int phs = q ^ (o & 7);
        bfr[nf] = *(const bf16x8*)(wb + o * 64 + phs * 8);
      }
      #pragma unroll
      for (int nf = 0; nf < 4; ++nf)
        #pragma unroll
        for (int mf = 0; mf < 2; ++mf)
          acc[mf][nf] = __builtin_amdgcn_mfma_f32_16x16x32_bf16(
              af[mf][kh * 8 + j], bfr[nf], acc[mf][nf], 0, 0, 0);
    }
    __builtin_amdgcn_s_setprio(0);

    if (kh) {                                    // expert end: gated drain
      f32x4 gq[2];
      #pragma unroll
      for (int mf = 0; mf < 2; ++mf)
        gq[mf] = *(const f32x4*)&gsh[e][wave * 32 + mf * 16 + (lane >> 4) * 4];
      #pragma unroll
      for (int mf = 0; mf < 2; ++mf)
        #pragma unroll
        for (int nf = 0; nf < 4; ++nf)
          #pragma unroll
          for (int rg = 0; rg < 4; ++rg)
            logits[mf][nf][rg] += gq[mf][rg] * acc[mf][nf][rg];
    }

    __builtin_amdgcn_s_barrier();                // all waves done reading buf
    buf ^= 1;
  }

  float* pout = partials + (size_t)eg * B_SZ * O_SZ + (size_t)row0 * O_SZ;
  #pragma unroll
  for (int mf = 0; mf < 2; ++mf)
    #pragma unroll
    for (int nf = 0; nf < 4; ++nf)
      #pragma unroll
      for (int rg = 0; rg < 4; ++rg) {
        int r = wave * 32 + mf * 16 + ((lane >> 4) << 2) + rg;
        int o = nf * 16 + (lane & 15);
        pout[(size_t)r * O_SZ + o] = logits[mf][nf][rg];
      }
}

// ---------------- reduce: sum partials + log_softmax (bias already in gemm) ----
__global__ __launch_bounds__(256)
void mtc_reduce(const float* __restrict__ partials, float* __restrict__ out) {
  int wave = threadIdx.x >> 6, lane = threadIdx.x & 63;
  int r = blockIdx.x * 4 + wave;                    // one 64-lane wave per row
  float s = 0.f;
  #pragma unroll
  for (int k = 0; k < EG_N; ++k)
    s += partials[(size_t)k * B_SZ * O_SZ + (size_t)r * O_SZ + lane];
  float m = s;
  #pragma unroll
  for (int off = 32; off; off >>= 1) m = fmaxf(m, __shfl_xor(m, off));
  float ex = expf(s - m), sum = ex;
  #pragma unroll
  for (int off = 32; off; off >>= 1) sum += __shfl_xor(sum, off);
  out[(size_t)r * O_SZ + lane] = s - m - logf(sum);
}

extern "C" void kernel_launch(void* const* d_in, const int* in_sizes, int n_in,
                              void* d_out, int out_size, void* d_ws, size_t ws_size,
                              hipStream_t stream) {
  const float* x    = (const float*)d_in[0];
  const float* ds   = (const float*)d_in[1];
  const float* ts   = (const float*)d_in[2];
  const float* W    = (const float*)d_in[3];
  const float* bias = (const float*)d_in[4];
  float* out = (float*)d_out;

  char* w = (char*)d_ws;
  __bf16* xb      = (__bf16*)(w);                   // 4 MB
  __bf16* wt      = (__bf16*)(w + (4ull  << 20));   // 8 MB
  float*  gT      = (float*) (w + (12ull << 20));   // 2 MB
  float*  parts   = (float*) (w + (14ull << 20));   // 16 MB

  prep_xg   <<<2048, 256, 0, stream>>>(x, xb, ds, ts, gT);
  prep_w    <<<1024, 256, 0, stream>>>(W, wt);
  mtc_gemm  <<< 512, 256, 0, stream>>>(xb, wt, gT, bias, parts);
  mtc_reduce<<<1024, 256, 0, stream>>>(parts, out);
}

// Round 16
// 116.649 us; speedup vs baseline: 1.1309x; 1.0073x over previous
//
#include <hip/hip_runtime.h>
#include <hip/hip_bf16.h>

typedef __bf16 bf16x8 __attribute__((ext_vector_type(8)));
typedef float  f32x4  __attribute__((ext_vector_type(4)));

#define B_SZ 4096
#define I_SZ 512
#define O_SZ 64
#define E_SZ 128
#define BM   128     // 4 waves x 32 rows
#define G_EXP 8      // experts per workgroup (K-split group size)
#define EG_N  16     // expert groups
#define MT_N  32     // m tiles (4096/128)

// ---------------- fused prep: x f32->bf16  +  gT[e][b] ----------------
__global__ void prep_xg(const float* __restrict__ x, __bf16* __restrict__ xb,
                        const float* __restrict__ ds, const float* __restrict__ ts,
                        float* __restrict__ gT) {
  int i = blockIdx.x * 256 + threadIdx.x;          // 524288 = B*I/4 = E*B
  float4 v = ((const float4*)x)[i];
  union { __bf16 h[4]; ushort4 u4; } pk;
  pk.h[0] = (__bf16)v.x; pk.h[1] = (__bf16)v.y;
  pk.h[2] = (__bf16)v.z; pk.h[3] = (__bf16)v.w;
  ((ushort4*)xb)[i] = pk.u4;
  int e = i >> 12, b = i & 4095;
  gT[i] = ds[b * 32 + (e >> 2)] * ts[b * 4 + (e & 3)];
}

// ---------------- prep: W [e][i][o] f32 -> wt [e][o][i] bf16 ----------------
__global__ void prep_w(const float* __restrict__ W, __bf16* __restrict__ wt) {
  __shared__ __bf16 tile[64][66];
  int e  = blockIdx.x >> 3;
  int it = blockIdx.x & 7;
  const float* src = W + (size_t)e * I_SZ * O_SZ + (size_t)it * 64 * O_SZ;
  #pragma unroll
  for (int s = 0; s < 16; ++s) {
    int idx = s * 256 + threadIdx.x;
    int r = idx >> 6, o = idx & 63;
    tile[o][r] = (__bf16)src[idx];
  }
  __syncthreads();
  __bf16* dst = wt + (size_t)e * O_SZ * I_SZ + it * 64;
  #pragma unroll
  for (int s = 0; s < 4; ++s) {
    int idx = s * 256 + threadIdx.x;
    int o = idx >> 4, c = (idx & 15) << 2;
    union { __bf16 h[4]; ushort4 u4; } q;
    q.h[0] = tile[o][c + 0]; q.h[1] = tile[o][c + 1];
    q.h[2] = tile[o][c + 2]; q.h[3] = tile[o][c + 3];
    *(ushort4*)&dst[(size_t)o * I_SZ + c] = q.u4;
  }
}

// ---------------- main: 2 independent blocks/CU + af remat fence --------------
// R15 structure byte-identical (512 blocks x 256 thr, 4 waves x 32 rows, 70KB LDS,
// 2 blocks/CU, phase = half-expert, counted vmcnt(8), chunked zero-conflict LDS)
// + THE FIX: R15's FETCH=282MB / VGPR=88 showed the compiler sank the af loads
// into the phase loop (re-loading 512B/thread x16 phases -> L2 thrash). The
// opaque asm redefinition makes af non-rematerializable; compiler keeps it
// resident (AGPR ok: 128 AGPR + ~100 VGPR = 228 <= 256). R9's config had af in
// AGPRs already (FETCH 21.5MB proved no re-loads), which is why R10's fence was
// a no-op there. Desync hypothesis finally gets a clean test here.
__global__ __launch_bounds__(256, 2)
void mtc_gemm(const __bf16* __restrict__ xb, const __bf16* __restrict__ wt,
              const float* __restrict__ gT, const float* __restrict__ bias,
              float* __restrict__ partials) {
  __shared__ __align__(16) __bf16 wsh[2][4][64 * 64];  // 2 buf x 4 chunks x 8KB = 64KB
  __shared__ float gsh[G_EXP][BM];                     // 4KB gates
  __shared__ float bsh[G_EXP][O_SZ];                   // 2KB bias

  const int tid  = threadIdx.x;
  const int wave = tid >> 6;                           // 0..3
  const int lane = tid & 63;

  // XCD swizzle: 512 blocks -> 64 consecutive per XCD
  int bid = (int)blockIdx.x;
  bid = (bid & 7) * 64 + (bid >> 3);
  const int mtile = bid & 31;
  const int eg    = bid >> 5;
  const int row0  = mtile * BM;
  const int e0    = eg * G_EXP;

  // stage half-expert (e, kh): 32KB = 4 chunks of [o][64k], 8 DMAs/thread.
  // dest linear: chunk[d>>1] byte (d&1)*4096 + tid*16  =>  o=(d&1)*32+(tid>>3),
  // phys slot p=tid&7; source slot sl = p^(o&7) (involution; read same XOR).
  auto stage = [&](int sbuf, int e, int kh) {
    const __bf16* wsrc = wt + (size_t)(e0 + e) * O_SZ * I_SZ + kh * 256;
    #pragma unroll
    for (int d = 0; d < 8; ++d) {
      int o  = (d & 1) * 32 + (tid >> 3);
      int sl = (tid & 7) ^ (o & 7);
      __builtin_amdgcn_global_load_lds(
          (const __attribute__((address_space(1))) void*)(wsrc + (size_t)o * I_SZ + (d >> 1) * 64 + sl * 8),
          (__attribute__((address_space(3))) void*)(&wsh[sbuf][d >> 1][(d & 1) * 2048 + tid * 8]),
          16, 0, 0);
    }
  };

  // prologue: stage (e0, kh0), overlap with gsh + bias + af loads
  stage(0, 0, 0);

  for (int idx = tid; idx < G_EXP * BM; idx += 256)
    gsh[idx >> 7][idx & 127] =
        gT[(size_t)(e0 + (idx >> 7)) * B_SZ + row0 + (idx & 127)];

  for (int idx = tid; idx < G_EXP * O_SZ; idx += 256)
    bsh[idx >> 6][idx & 63] = bias[(size_t)e0 * O_SZ + idx];

  // af[mf][jg] = x[row0+wave*32+mf*16+(lane&15)][jg*32+(lane>>4)*8 ..+8]  (full K)
  bf16x8 af[2][16];
  {
    const __bf16* xr = xb + (size_t)(row0 + wave * 32 + (lane & 15)) * I_SZ
                          + (lane >> 4) * 8;
    #pragma unroll
    for (int mf = 0; mf < 2; ++mf)
      #pragma unroll
      for (int jg = 0; jg < 16; ++jg)
        af[mf][jg] = *(const bf16x8*)(xr + mf * 16 * I_SZ + jg * 32);
  }
  // REMAT FENCE: opaque redefinition -> af cannot be re-derived from xb inside
  // the phase loop (R15's 282MB FETCH was exactly this sinking).
  #pragma unroll
  for (int mf = 0; mf < 2; ++mf)
    #pragma unroll
    for (int jg = 0; jg < 16; ++jg)
      asm volatile("" : "+v"(af[mf][jg]));

  __syncthreads();                     // drains DMA + af + bias + gsh (vmcnt->0)

  f32x4 logits[2][4] = {};
  f32x4 acc[2][4];
  int buf = 0;
  for (int ph = 0; ph < 2 * G_EXP; ++ph) {       // phase = (expert e, k-half kh)
    const int e  = ph >> 1;
    const int kh = ph & 1;
    if (ph < 2 * G_EXP - 1) {
      stage(buf ^ 1, (ph + 1) >> 1, (ph + 1) & 1);     // 8 DMAs, FIFO
      asm volatile("s_waitcnt vmcnt(8)" ::: "memory"); // this phase's 8 landed
    } else {
      asm volatile("s_waitcnt vmcnt(0)" ::: "memory");
    }
    __builtin_amdgcn_s_barrier();                // buf ready for all 4 waves

    if (!kh) {                                   // expert start: bias -> acc
      float bv[4];
      #pragma unroll
      for (int nf = 0; nf < 4; ++nf)
        bv[nf] = bsh[e][nf * 16 + (lane & 15)];
      #pragma unroll
      for (int mf = 0; mf < 2; ++mf)
        #pragma unroll
        for (int nf = 0; nf < 4; ++nf)
          acc[mf][nf] = (f32x4){bv[nf], bv[nf], bv[nf], bv[nf]};
    }

    __builtin_amdgcn_s_setprio(1);
    #pragma unroll
    for (int j = 0; j < 8; ++j) {                // k-quarter steps; chunk = j>>1
      const __bf16* wb = &wsh[buf][j >> 1][0];
      bf16x8 bfr[4];
      #pragma unroll
      for (int nf = 0; nf < 4; ++nf) {
        int o  = nf * 16 + (lane & 15);
        int q  = (j & 1) * 4 + (lane >> 4);
        int phs = q ^ (o & 7);
        bfr[nf] = *(const bf16x8*)(wb + o * 64 + phs * 8);
      }
      #pragma unroll
      for (int nf = 0; nf < 4; ++nf)
        #pragma unroll
        for (int mf = 0; mf < 2; ++mf)
          acc[mf][nf] = __builtin_amdgcn_mfma_f32_16x16x32_bf16(
              af[mf][kh * 8 + j], bfr[nf], acc[mf][nf], 0, 0, 0);
    }
    __builtin_amdgcn_s_setprio(0);

    if (kh) {                                    // expert end: gated drain
      f32x4 gq[2];
      #pragma unroll
      for (int mf = 0; mf < 2; ++mf)
        gq[mf] = *(const f32x4*)&gsh[e][wave * 32 + mf * 16 + (lane >> 4) * 4];
      #pragma unroll
      for (int mf = 0; mf < 2; ++mf)
        #pragma unroll
        for (int nf = 0; nf < 4; ++nf)
          #pragma unroll
          for (int rg = 0; rg < 4; ++rg)
            logits[mf][nf][rg] += gq[mf][rg] * acc[mf][nf][rg];
    }

    __builtin_amdgcn_s_barrier();                // all waves done reading buf
    buf ^= 1;
  }

  float* pout = partials + (size_t)eg * B_SZ * O_SZ + (size_t)row0 * O_SZ;
  #pragma unroll
  for (int mf = 0; mf < 2; ++mf)
    #pragma unroll
    for (int nf = 0; nf < 4; ++nf)
      #pragma unroll
      for (int rg = 0; rg < 4; ++rg) {
        int r = wave * 32 + mf * 16 + ((lane >> 4) << 2) + rg;
        int o = nf * 16 + (lane & 15);
        pout[(size_t)r * O_SZ + o] = logits[mf][nf][rg];
      }
}

// ---------------- reduce: sum partials + log_softmax (bias already in gemm) ----
__global__ __launch_bounds__(256)
void mtc_reduce(const float* __restrict__ partials, float* __restrict__ out) {
  int wave = threadIdx.x >> 6, lane = threadIdx.x & 63;
  int r = blockIdx.x * 4 + wave;                    // one 64-lane wave per row
  float s = 0.f;
  #pragma unroll
  for (int k = 0; k < EG_N; ++k)
    s += partials[(size_t)k * B_SZ * O_SZ + (size_t)r * O_SZ + lane];
  float m = s;
  #pragma unroll
  for (int off = 32; off; off >>= 1) m = fmaxf(m, __shfl_xor(m, off));
  float ex = expf(s - m), sum = ex;
  #pragma unroll
  for (int off = 32; off; off >>= 1) sum += __shfl_xor(sum, off);
  out[(size_t)r * O_SZ + lane] = s - m - logf(sum);
}

extern "C" void kernel_launch(void* const* d_in, const int* in_sizes, int n_in,
                              void* d_out, int out_size, void* d_ws, size_t ws_size,
                              hipStream_t stream) {
  const float* x    = (const float*)d_in[0];
  const float* ds   = (const float*)d_in[1];
  const float* ts   = (const float*)d_in[2];
  const float* W    = (const float*)d_in[3];
  const float* bias = (const float*)d_in[4];
  float* out = (float*)d_out;

  char* w = (char*)d_ws;
  __bf16* xb      = (__bf16*)(w);                   // 4 MB
  __bf16* wt      = (__bf16*)(w + (4ull  << 20));   // 8 MB
  float*  gT      = (float*) (w + (12ull << 20));   // 2 MB
  float*  parts   = (float*) (w + (14ull << 20));   // 16 MB

  prep_xg   <<<2048, 256, 0, stream>>>(x, xb, ds, ts, gT);
  prep_w    <<<1024, 256, 0, stream>>>(W, wt);
  mtc_gemm  <<< 512, 256, 0, stream>>>(xb, wt, gT, bias, parts);
  mtc_reduce<<<1024, 256, 0, stream>>>(parts, out);
}

// Round 17
// 60.796 us; speedup vs baseline: 2.1699x; 1.9187x over previous
//
#include <hip/hip_runtime.h>
#include <hip/hip_bf16.h>

typedef __bf16 bf16x8 __attribute__((ext_vector_type(8)));
typedef float  f32x4  __attribute__((ext_vector_type(4)));

#define B_SZ 4096
#define I_SZ 512
#define O_SZ 64
#define E_SZ 128
#define BM   256
#define G_EXP 8      // experts per workgroup (K-split group size)
#define EG_N  16     // expert groups
#define MT_N  16     // m tiles (4096/256)

// ---------------- prep: W [e][i][o] f32 -> wt [e][o][i] bf16 ----------------
__global__ void prep_w(const float* __restrict__ W, __bf16* __restrict__ wt) {
  __shared__ __bf16 tile[64][66];
  int e  = blockIdx.x >> 3;
  int it = blockIdx.x & 7;
  const float* src = W + (size_t)e * I_SZ * O_SZ + (size_t)it * 64 * O_SZ;
  #pragma unroll
  for (int s = 0; s < 16; ++s) {
    int idx = s * 256 + threadIdx.x;
    int r = idx >> 6, o = idx & 63;
    tile[o][r] = (__bf16)src[idx];
  }
  __syncthreads();
  __bf16* dst = wt + (size_t)e * O_SZ * I_SZ + it * 64;
  #pragma unroll
  for (int s = 0; s < 4; ++s) {
    int idx = s * 256 + threadIdx.x;
    int o = idx >> 4, c = (idx & 15) << 2;
    union { __bf16 h[4]; ushort4 u4; } q;
    q.h[0] = tile[o][c + 0]; q.h[1] = tile[o][c + 1];
    q.h[2] = tile[o][c + 2]; q.h[3] = tile[o][c + 3];
    *(ushort4*)&dst[(size_t)o * I_SZ + c] = q.u4;
  }
}

// ---------------- main: R9 core (verified best) + fused x-convert/gates -------
// 8 waves x 32 rows (Mf=2 of 16) = BM 256; mfma_f32_16x16x32_bf16, Nf=4 covers O=64.
// Core loop BYTE-IDENTICAL to R9 (48.4us, no spill, 0 conflicts): chunked
// [buf][kc][o*64+slot*8] LDS, 2 barriers + counted vmcnt(8)/expert, bias in LDS.
// New (prologue only): x read as f32 + converted to bf16 af in-register (kills
// the prep_xg pass), gates g = ds*ts computed directly into gsh (kills gT).
// Partials written as bf16 (R13-verified): halves parts traffic.
__global__ __launch_bounds__(512, 2)
void mtc_gemm(const float* __restrict__ x, const __bf16* __restrict__ wt,
              const float* __restrict__ ds, const float* __restrict__ ts,
              const float* __restrict__ bias, __bf16* __restrict__ partials) {
  __shared__ __align__(16) __bf16 wsh[2][8][64 * 64];  // [buf][kc][o*64+slot*8] 8KB chunks
  __shared__ float gsh[G_EXP][BM];                     // 8KB gates
  __shared__ float bsh[G_EXP][O_SZ];                   // 2KB bias

  const int tid  = threadIdx.x;
  const int wave = tid >> 6;
  const int lane = tid & 63;

  // XCD swizzle: 256 blocks -> 32 consecutive per XCD
  int bid = (int)blockIdx.x;
  bid = (bid & 7) * 32 + (bid >> 3);
  const int mtile = bid & 15;
  const int eg    = bid >> 4;
  const int row0  = mtile * BM;
  const int e0    = eg * G_EXP;

  // stage whole expert e into wsh[sbuf]: 8 DMAs/thread (512 thr x 16B x 8 = 64KB).
  // dest linear => [o=tid>>3][slot p=tid&7]; source slot sl = p^(o&7) (involution).
  auto stage = [&](int sbuf, int e) {
    const __bf16* wsrc = wt + (size_t)(e0 + e) * O_SZ * I_SZ;
    int o = tid >> 3, p = tid & 7;
    int sl = p ^ (o & 7);
    #pragma unroll
    for (int kc = 0; kc < 8; ++kc) {
      __builtin_amdgcn_global_load_lds(
          (const __attribute__((address_space(1))) void*)(wsrc + (size_t)o * I_SZ + kc * 64 + sl * 8),
          (__attribute__((address_space(3))) void*)(&wsh[sbuf][kc][wave * 512]),
          16, 0, 0);
    }
  };

  // prologue: stage expert 0, overlap with gates + bias + af loads
  stage(0, 0);

  // gates: gsh[k][r] = ds[row0+r][(e0+k)>>2] * ts[row0+r][k&3]  (tiny, L2-hot)
  for (int idx = tid; idx < G_EXP * BM; idx += 512) {
    int k = idx >> 8, r = idx & 255;
    gsh[k][r] = ds[(size_t)(row0 + r) * 32 + ((e0 + k) >> 2)]
              * ts[(size_t)(row0 + r) * 4 + (k & 3)];
  }

  bsh[tid >> 6][tid & 63] = bias[(size_t)e0 * O_SZ + tid];   // 512 = G_EXP*O_SZ

  // x A-fragments from f32, converted once:
  // af[mf][j] = (bf16) x[row0+wave*32+mf*16+(lane&15)][j*32+(lane>>4)*8 ..+8]
  bf16x8 af[2][16];
  {
    const float* xr = x + (size_t)(row0 + wave * 32 + (lane & 15)) * I_SZ
                        + (lane >> 4) * 8;
    #pragma unroll
    for (int mf = 0; mf < 2; ++mf)
      #pragma unroll
      for (int j = 0; j < 16; ++j) {
        f32x4 a = *(const f32x4*)(xr + mf * 16 * I_SZ + j * 32);
        f32x4 b = *(const f32x4*)(xr + mf * 16 * I_SZ + j * 32 + 4);
        bf16x8 v;
        v[0] = (__bf16)a[0]; v[1] = (__bf16)a[1];
        v[2] = (__bf16)a[2]; v[3] = (__bf16)a[3];
        v[4] = (__bf16)b[0]; v[5] = (__bf16)b[1];
        v[6] = (__bf16)b[2]; v[7] = (__bf16)b[3];
        af[mf][j] = v;
      }
  }

  __syncthreads();                     // drains DMA(e0) + af + bias + gsh (vmcnt->0)

  f32x4 logits[2][4] = {};
  int buf = 0;
  for (int e = 0; e < G_EXP; ++e) {
    if (e < G_EXP - 1) {
      stage(buf ^ 1, e + 1);                       // 8 DMAs into other buffer
      asm volatile("s_waitcnt vmcnt(8)" ::: "memory");   // stage(e) landed
    } else {
      asm volatile("s_waitcnt vmcnt(0)" ::: "memory");
    }
    __builtin_amdgcn_s_barrier();                  // buf ready for all waves

    // bias from LDS: 4 regs live, lgkmcnt (doesn't disturb vmcnt counting)
    float bv[4];
    #pragma unroll
    for (int nf = 0; nf < 4; ++nf)
      bv[nf] = bsh[e][nf * 16 + (lane & 15)];
    f32x4 acc[2][4];
    #pragma unroll
    for (int mf = 0; mf < 2; ++mf)
      #pragma unroll
      for (int nf = 0; nf < 4; ++nf)
        acc[mf][nf] = (f32x4){bv[nf], bv[nf], bv[nf], bv[nf]};

    __builtin_amdgcn_s_setprio(1);
    #pragma unroll
    for (int j = 0; j < 16; ++j) {                 // K-steps of 32; chunk = j>>1
      const __bf16* wb = &wsh[buf][j >> 1][0];
      bf16x8 bfr[4];
      #pragma unroll
      for (int nf = 0; nf < 4; ++nf) {
        int o  = nf * 16 + (lane & 15);
        int q  = (j & 1) * 4 + (lane >> 4);
        int ph = q ^ (o & 7);
        bfr[nf] = *(const bf16x8*)(wb + o * 64 + ph * 8);
      }
      #pragma unroll
      for (int nf = 0; nf < 4; ++nf)
        #pragma unroll
        for (int mf = 0; mf < 2; ++mf)
          acc[mf][nf] = __builtin_amdgcn_mfma_f32_16x16x32_bf16(
              af[mf][j], bfr[nf], acc[mf][nf], 0, 0, 0);
    }
    __builtin_amdgcn_s_setprio(0);

    // drain: logits += g[row,e] * (xW+b).  C/D: col=lane&15, row=(lane>>4)*4+rg
    f32x4 gq[2];
    #pragma unroll
    for (int mf = 0; mf < 2; ++mf)
      gq[mf] = *(const f32x4*)&gsh[e][wave * 32 + mf * 16 + (lane >> 4) * 4];
    #pragma unroll
    for (int mf = 0; mf < 2; ++mf)
      #pragma unroll
      for (int nf = 0; nf < 4; ++nf)
        #pragma unroll
        for (int rg = 0; rg < 4; ++rg)
          logits[mf][nf][rg] += gq[mf][rg] * acc[mf][nf][rg];

    __builtin_amdgcn_s_barrier();                  // all waves done reading buf
    buf ^= 1;
  }

  __bf16* pout = partials + (size_t)eg * B_SZ * O_SZ + (size_t)row0 * O_SZ;
  #pragma unroll
  for (int mf = 0; mf < 2; ++mf)
    #pragma unroll
    for (int nf = 0; nf < 4; ++nf)
      #pragma unroll
      for (int rg = 0; rg < 4; ++rg) {
        int r = wave * 32 + mf * 16 + ((lane >> 4) << 2) + rg;
        int o = nf * 16 + (lane & 15);
        pout[(size_t)r * O_SZ + o] = (__bf16)logits[mf][nf][rg];
      }
}

// ---------------- reduce: sum 16 bf16 partial slabs + log_softmax --------------
__global__ __launch_bounds__(256)
void mtc_reduce(const __bf16* __restrict__ partials, float* __restrict__ out) {
  int wave = threadIdx.x >> 6, lane = threadIdx.x & 63;
  int r = blockIdx.x * 4 + wave;                    // one 64-lane wave per row
  float s = 0.f;
  #pragma unroll
  for (int k = 0; k < EG_N; ++k)
    s += (float)partials[(size_t)k * B_SZ * O_SZ + (size_t)r * O_SZ + lane];
  float m = s;
  #pragma unroll
  for (int off = 32; off; off >>= 1) m = fmaxf(m, __shfl_xor(m, off));
  float ex = expf(s - m), sum = ex;
  #pragma unroll
  for (int off = 32; off; off >>= 1) sum += __shfl_xor(sum, off);
  out[(size_t)r * O_SZ + lane] = s - m - logf(sum);
}

extern "C" void kernel_launch(void* const* d_in, const int* in_sizes, int n_in,
                              void* d_out, int out_size, void* d_ws, size_t ws_size,
                              hipStream_t stream) {
  const float* x    = (const float*)d_in[0];
  const float* ds   = (const float*)d_in[1];
  const float* ts   = (const float*)d_in[2];
  const float* W    = (const float*)d_in[3];
  const float* bias = (const float*)d_in[4];
  float* out = (float*)d_out;

  char* w = (char*)d_ws;
  __bf16* wt      = (__bf16*)(w);                   // 8 MB
  __bf16* parts   = (__bf16*)(w + (8ull << 20));    // 8 MB (16 slabs x 512KB)

  prep_w    <<<1024, 256, 0, stream>>>(W, wt);
  mtc_gemm  <<< 256, 512, 0, stream>>>(x, wt, ds, ts, bias, parts);
  mtc_reduce<<<1024, 256, 0, stream>>>(parts, out);
}